// Round 1
// baseline (95.408 us; speedup 1.0000x reference)
//
#include <hip/hip_runtime.h>
#include <stdint.h>

#define NROW 16384
#define DDIM 128
#define ROWB (DDIM * 2)   // bytes per row of bf16 z

constexpr int MT  = 256;            // rows per block
constexpr int NB  = 64;             // cols per j-tile
constexpr int NCH = 8;              // column chunks (grid.x)
constexpr int CPB = NROW / NCH;     // cols per block = 2048
constexpr int JT  = CPB / NB;       // j-tiles per block = 32

typedef __bf16 bf16x8 __attribute__((ext_vector_type(8)));
typedef float  f32x4  __attribute__((ext_vector_type(4)));
typedef int    i32x4  __attribute__((ext_vector_type(4)));

typedef const uint32_t __attribute__((address_space(1)))* gptr_t;
typedef uint32_t __attribute__((address_space(3)))*       lptr_t;

__device__ __forceinline__ unsigned short f2bf(float x) {
  union { float f; uint32_t u; } c; c.f = x;
  uint32_t u = c.u + 0x7fffu + ((c.u >> 16) & 1u);   // RNE
  return (unsigned short)(u >> 16);
}

// fp32 -> bf16 with full scale folded in: (1/T) * sqrt(log2(e))
// so the MFMA accumulator equals a*log2(e), ready for v_exp_f32 (exp2).
__global__ __launch_bounds__(256) void prep_kernel(const float* __restrict__ z,
                                                   unsigned short* __restrict__ zs,
                                                   float* __restrict__ s) {
  const float SC = 12.011224087864498f;  // 10 * sqrt(1.4426950408889634)
  int t = blockIdx.x * 256 + threadIdx.x;         // 0 .. NROW*DDIM/4-1
  float4 v = reinterpret_cast<const float4*>(z)[t];
  ushort4 o;
  o.x = f2bf(v.x * SC); o.y = f2bf(v.y * SC);
  o.z = f2bf(v.z * SC); o.w = f2bf(v.w * SC);
  reinterpret_cast<ushort4*>(zs)[t] = o;
  if (t < NROW) s[t] = 0.0f;                      // rowsum accumulator
}

__global__ __launch_bounds__(256, 2) void gemm_exp_kernel(const unsigned short* __restrict__ zs,
                                                          float* __restrict__ s) {
  __shared__ __align__(16) char smem[2 * NB * ROWB];   // 32 KB: B double-buffer
  const int tid  = threadIdx.x;
  const int lane = tid & 63;
  const int wid  = tid >> 6;
  const int rowBase = blockIdx.y * MT;
  const int colBase = blockIdx.x * CPB;
  const char* zb = (const char*)zs;

  // ---- A fragments: wave owns rows [rowBase + wid*64, +64), all K=128 ----
  // 16x16x32 A layout: row = lane&15, k = (lane>>4)*8 + e  -> 16B/lane loads
  bf16x8 afrag[4][4];   // [mf][ks]
  {
    const int r0 = rowBase + wid * 64 + (lane & 15);
    const int kb = (lane >> 4) << 4;
#pragma unroll
    for (int mf = 0; mf < 4; ++mf)
#pragma unroll
      for (int ks = 0; ks < 4; ++ks) {
        i32x4 raw = *reinterpret_cast<const i32x4*>(
            zb + (size_t)(r0 + mf * 16) * ROWB + ks * 64 + kb);
        afrag[mf][ks] = __builtin_bit_cast(bf16x8, raw);
      }
  }

  float rs[4][4];
#pragma unroll
  for (int mf = 0; mf < 4; ++mf)
#pragma unroll
    for (int r = 0; r < 4; ++r) rs[mf][r] = 0.0f;

  // Stage one 64x128 bf16 B-tile (16 KB) into LDS buffer `buf`.
  // Linear LDS dest (global_load_lds requirement) + inverse-XOR-swizzled
  // global source; reads apply the same involution (rule #21).
#define STAGE_B(buf, jtile)                                                      \
  {                                                                              \
    const int base_ = (buf) * (NB * ROWB);                                       \
    _Pragma("unroll")                                                            \
    for (int i_ = 0; i_ < 4; ++i_) {                                             \
      const int destByte_ = wid * 4096 + i_ * 1024 + lane * 16;                  \
      const int r_  = destByte_ >> 8;            /* row in tile */               \
      const int cb_ = destByte_ & 0xF0;          /* 16B chunk in row */          \
      const int srcByte_ = (colBase + (jtile) * NB + r_) * ROWB                  \
                           + (cb_ ^ ((r_ & 7) << 4));                            \
      __builtin_amdgcn_global_load_lds((gptr_t)(zb + srcByte_),                  \
                                       (lptr_t)(smem + base_ + wid * 4096 + i_ * 1024), \
                                       16, 0, 0);                                \
    }                                                                            \
  }

  STAGE_B(0, 0);

  for (int jt = 0; jt < JT; ++jt) {
    const int cur = jt & 1;
    if (jt + 1 < JT) {
      STAGE_B(cur ^ 1, jt + 1);
      asm volatile("s_waitcnt vmcnt(4)" ::: "memory");  // current tile landed
    } else {
      asm volatile("s_waitcnt vmcnt(0)" ::: "memory");
    }
    __builtin_amdgcn_s_barrier();

    f32x4 acc[4][4];
#pragma unroll
    for (int mf = 0; mf < 4; ++mf)
#pragma unroll
      for (int nf = 0; nf < 4; ++nf) {
        f32x4 zv = {0.f, 0.f, 0.f, 0.f};
        acc[mf][nf] = zv;
      }

    const char* bufp = smem + cur * (NB * ROWB);
#pragma unroll
    for (int ks = 0; ks < 4; ++ks) {
      bf16x8 bfrag[4];
#pragma unroll
      for (int nf = 0; nf < 4; ++nf) {
        const int r   = nf * 16 + (lane & 15);
        const int kb  = ks * 64 + ((lane >> 4) << 4);
        const int off = r * ROWB + (kb ^ ((r & 7) << 4));
        i32x4 raw = *reinterpret_cast<const i32x4*>(bufp + off);
        bfrag[nf] = __builtin_bit_cast(bf16x8, raw);
      }
#pragma unroll
      for (int mf = 0; mf < 4; ++mf)
#pragma unroll
        for (int nf = 0; nf < 4; ++nf)
          acc[mf][nf] = __builtin_amdgcn_mfma_f32_16x16x32_bf16(
              afrag[mf][ks], bfrag[nf], acc[mf][nf], 0, 0, 0);
    }

    // acc already holds a*log2(e)  ->  exp(a) = exp2(acc)
#pragma unroll
    for (int mf = 0; mf < 4; ++mf)
#pragma unroll
      for (int nf = 0; nf < 4; ++nf) {
        f32x4 a4 = acc[mf][nf];
#pragma unroll
        for (int r = 0; r < 4; ++r)
          rs[mf][r] += __builtin_amdgcn_exp2f(a4[r]);
      }

    __builtin_amdgcn_s_barrier();   // all waves done reading buf[cur]
  }

  // C/D layout: col = lane&15 (summed out), row = (lane>>4)*4 + reg.
  // Reduce across the 16 column-lanes, then one atomicAdd per row.
#pragma unroll
  for (int mf = 0; mf < 4; ++mf)
#pragma unroll
    for (int r = 0; r < 4; ++r) {
      float v = rs[mf][r];
      v += __shfl_xor(v, 1);
      v += __shfl_xor(v, 2);
      v += __shfl_xor(v, 4);
      v += __shfl_xor(v, 8);
      if ((lane & 15) == 0) {
        const int row = rowBase + wid * 64 + mf * 16 + ((lane >> 4) << 2) + r;
        atomicAdd(&s[row], v);
      }
    }
#undef STAGE_B
}

__global__ __launch_bounds__(256) void reduce_kernel(const float* __restrict__ s,
                                                     float* __restrict__ out) {
  const int tid = threadIdx.x;
  float acc = 0.0f;
  for (int i = tid; i < NROW; i += 256) acc += logf(s[i]);
#pragma unroll
  for (int m = 32; m >= 1; m >>= 1) acc += __shfl_xor(acc, m);
  __shared__ float wsum[4];
  if ((tid & 63) == 0) wsum[tid >> 6] = acc;
  __syncthreads();
  if (tid == 0) {
    float t = wsum[0] + wsum[1] + wsum[2] + wsum[3];
    out[0] = logf((float)NROW) - t / (float)NROW;
  }
}

extern "C" void kernel_launch(void* const* d_in, const int* in_sizes, int n_in,
                              void* d_out, int out_size, void* d_ws, size_t ws_size,
                              hipStream_t stream) {
  const float* z = (const float*)d_in[0];
  unsigned short* zs = (unsigned short*)d_ws;                       // 4 MB bf16
  float* s = (float*)((char*)d_ws + (size_t)NROW * DDIM * 2);       // 64 KB rowsums
  float* out = (float*)d_out;

  prep_kernel<<<dim3(NROW * DDIM / 4 / 256), dim3(256), 0, stream>>>(z, zs, s);
  gemm_exp_kernel<<<dim3(NCH, NROW / MT), dim3(256), 0, stream>>>(zs, s);
  reduce_kernel<<<dim3(1), dim3(256), 0, stream>>>(s, out);
}